// Round 18
// baseline (26.364 us; speedup 1.0000x reference)
//
#include <hip/hip_runtime.h>
#include <float.h>

#define NB 68                 // padded bins (64 + 2*2)
#define NJ (NB * NB)          // 4624 joint bins
#define NSLICE 8              // J slices (flush chain depth ~125/8 ~ 16)
#define HTPB 1024             // k_hist threads per block
#define MMBLK 125             // blocks per batch (125*1024 = 128000 float4s)
#define SCALE 2097152.0f      // 2^21 fixed-point scale

// ws layout (bytes):
// [64 .. 64+2*128*16)  P: per-block minmax partials, float4 {smx,smn,tmx,tmn}
// [4160 .. +NSLICE*2*NJ*8)  J: u64 joint totals [slice][b][NJ]

// Kernel 1: minmax block partials + zero J slices. One float4 of src+tgt
// per thread (all loads in flight), block reduce, one plain float4 store.
__global__ __launch_bounds__(1024) void k_prep(const float* __restrict__ src,
                                               const float* __restrict__ tgt,
                                               float4* __restrict__ P,
                                               unsigned long long* __restrict__ J,
                                               int n4) {
    __shared__ float red[16][4];
    const int b = blockIdx.y;
    const int lin = (b * gridDim.x + blockIdx.x) * 1024 + threadIdx.x;
    for (int j = lin; j < NSLICE * 2 * NJ; j += 2 * MMBLK * 1024) J[j] = 0ull;

    const int i = blockIdx.x * 1024 + threadIdx.x;
    float smx = -FLT_MAX, smn = FLT_MAX, tmx = -FLT_MAX, tmn = FLT_MAX;
    if (i < n4) {
        float4 v = ((const float4*)src)[(size_t)b * n4 + i];
        float4 w = ((const float4*)tgt)[(size_t)b * n4 + i];
        smx = fmaxf(fmaxf(v.x, v.y), fmaxf(v.z, v.w));
        smn = fminf(fminf(v.x, v.y), fminf(v.z, v.w));
        tmx = fmaxf(fmaxf(w.x, w.y), fmaxf(w.z, w.w));
        tmn = fminf(fminf(w.x, w.y), fminf(w.z, w.w));
    }
#pragma unroll
    for (int m = 1; m < 64; m <<= 1) {
        smx = fmaxf(smx, __shfl_xor(smx, m));
        smn = fminf(smn, __shfl_xor(smn, m));
        tmx = fmaxf(tmx, __shfl_xor(tmx, m));
        tmn = fminf(tmn, __shfl_xor(tmn, m));
    }
    const int wave = threadIdx.x >> 6;
    if ((threadIdx.x & 63) == 0) {
        red[wave][0] = smx;
        red[wave][1] = smn;
        red[wave][2] = tmx;
        red[wave][3] = tmn;
    }
    __syncthreads();
    if (threadIdx.x == 0) {
#pragma unroll
        for (int k = 1; k < 16; ++k) {
            smx = fmaxf(smx, red[k][0]);
            smn = fminf(smn, red[k][1]);
            tmx = fmaxf(tmx, red[k][2]);
            tmn = fminf(tmn, red[k][3]);
        }
        P[b * 128 + blockIdx.x] = make_float4(smx, smn, tmx, tmn);
    }
}

__device__ __forceinline__ float bspl(float d) {
    float ad = fabsf(d);
    float a = (3.0f * ad * ad * ad - 6.0f * ad * ad + 4.0f) * (1.0f / 6.0f);
    float t = 2.0f - ad;
    float c = t * t * t * (1.0f / 6.0f);
    return ad < 1.0f ? a : (ad < 2.0f ? c : 0.0f);
}

__device__ __forceinline__ void vox1(float sv, float tv, unsigned* jh,
                                     float spad, float sinv, float tpad,
                                     float tinv) {
    float posS = (sv - spad) * sinv;
    float fS = floorf(posS);
    fS = fminf(fmaxf(fS, 2.0f), 65.0f);
    int si = (int)fS - 1;
    float dS = posS - fS;
    float a[4] = {bspl(dS + 1.0f), bspl(dS), bspl(dS - 1.0f), bspl(dS - 2.0f)};

    float posT = (tv - tpad) * tinv;
    float fT = floorf(posT);
    fT = fminf(fmaxf(fT, 2.0f), 65.0f);
    int ti = (int)fT - 1;
    float dT = posT - fT;
    float bb[4] = {bspl(dT + 1.0f), bspl(dT), bspl(dT - 1.0f), bspl(dT - 2.0f)};

    unsigned* base = jh + si * NB + ti;
#pragma unroll
    for (int r = 0; r < 4; ++r) {
#pragma unroll
        for (int c = 0; c < 4; ++c) {
            unsigned q = (unsigned)(a[r] * bb[c] * SCALE + 0.5f);
            atomicAdd(&base[r * NB + c], q);
        }
    }
}

// Kernel 2: 1024 threads/block, 125 blocks/batch (1 float4/thread,
// 16 waves/CU), LDS u32 hist (2 lane-interleaved copies). u64 atomic
// flush into slice (bx & 7) with per-block rotation: per-address chain
// depth ~16. Integer -> deterministic.
__global__ __launch_bounds__(HTPB) void k_hist(
    const float* __restrict__ src, const float* __restrict__ tgt,
    const float4* __restrict__ P, unsigned long long* __restrict__ J, int n4) {
    __shared__ unsigned lh[2 * NJ];
    __shared__ float pmm[8], mmv[4];
    const int tid = threadIdx.x;
    const int b = blockIdx.y;

    // inline reduce of the 125 minmax partials (2 waves)
    if (tid < 128) {
        float smx = -FLT_MAX, smn = FLT_MAX, tmx = -FLT_MAX, tmn = FLT_MAX;
        if (tid < MMBLK) {
            float4 v = P[b * 128 + tid];
            smx = v.x; smn = v.y; tmx = v.z; tmn = v.w;
        }
#pragma unroll
        for (int m = 1; m < 64; m <<= 1) {
            smx = fmaxf(smx, __shfl_xor(smx, m));
            smn = fminf(smn, __shfl_xor(smn, m));
            tmx = fmaxf(tmx, __shfl_xor(tmx, m));
            tmn = fminf(tmn, __shfl_xor(tmn, m));
        }
        if ((tid & 63) == 0) {
            int w = tid >> 6;
            pmm[w * 4 + 0] = smx;
            pmm[w * 4 + 1] = smn;
            pmm[w * 4 + 2] = tmx;
            pmm[w * 4 + 3] = tmn;
        }
    }
    // zero LDS hist concurrently
    uint4* z4 = (uint4*)lh;
    const uint4 zz = make_uint4(0u, 0u, 0u, 0u);
    for (int i = tid; i < (2 * NJ) / 4; i += HTPB) z4[i] = zz;
    __syncthreads();
    if (tid == 0) {
        mmv[0] = fmaxf(pmm[0], pmm[4]);   // smx
        mmv[1] = fminf(pmm[1], pmm[5]);   // smn
        mmv[2] = fmaxf(pmm[2], pmm[6]);   // tmx
        mmv[3] = fminf(pmm[3], pmm[7]);   // tmn
    }
    __syncthreads();

    const float sbw = (mmv[0] - mmv[1]) * (1.0f / 64.0f);
    const float tbw = (mmv[2] - mmv[3]) * (1.0f / 64.0f);
    const float sinv = 1.0f / sbw, tinv = 1.0f / tbw;
    const float spad = mmv[1] - 2.0f * sbw;
    const float tpad = mmv[3] - 2.0f * tbw;

    unsigned* jh = lh + (tid & 1) * NJ;    // lane-interleaved copies
    const int i0 = blockIdx.x * HTPB + tid;
    if (i0 < n4) {
        float4 sA = ((const float4*)src)[(size_t)b * n4 + i0];
        float4 tA = ((const float4*)tgt)[(size_t)b * n4 + i0];
        vox1(sA.x, tA.x, jh, spad, sinv, tpad, tinv);
        vox1(sA.y, tA.y, jh, spad, sinv, tpad, tinv);
        vox1(sA.z, tA.z, jh, spad, sinv, tpad, tinv);
        vox1(sA.w, tA.w, jh, spad, sinv, tpad, tinv);
    }
    __syncthreads();

    // rotated, sliced flush
    const int rot = (blockIdx.x * 1327) % NJ;
    unsigned long long* Jb =
        J + ((size_t)(blockIdx.x & (NSLICE - 1)) * 2 + b) * NJ;
    for (int k = tid; k < NJ; k += HTPB) {
        int i = k + rot;
        if (i >= NJ) i -= NJ;
        unsigned s = lh[i] + lh[NJ + i];
        if (s) atomicAdd(&Jb[i], (unsigned long long)s);
    }
}

// Kernel 3: one 1024-thread block per batch. Sum the 8 J slices while
// staging into LDS (emitting joint density), then row/col sums as 8-way
// parallel partials over LDS. Analytic total nvox*2^21.
__global__ __launch_bounds__(1024) void k_norm(
    const unsigned long long* __restrict__ J, float* __restrict__ out,
    double inv) {
    __shared__ float jf[NJ];
    __shared__ float part[NB][8];
    const int b = blockIdx.x;
    const int tid = threadIdx.x;

    for (int i = tid; i < NJ; i += 1024) {
        unsigned long long s = 0ull;
#pragma unroll
        for (int sl = 0; sl < NSLICE; ++sl)
            s += J[((size_t)sl * 2 + b) * NJ + i];
        float f = (float)((double)s * inv);
        jf[i] = f;
        out[4 * NB + b * NJ + i] = f;
    }
    __syncthreads();

    if (tid < 8 * NB) {                       // rows: 8 partials per row
        int r = tid >> 3, k = tid & 7;
        float s = 0.0f;
#pragma unroll
        for (int j = 0; j < 9; ++j) {
            int c = k + 8 * j;
            if (c < NB) s += jf[r * NB + c];
        }
        part[r][k] = s;
    }
    __syncthreads();
    if (tid < NB) {
        float s = part[tid][0] + part[tid][1] + part[tid][2] + part[tid][3] +
                  part[tid][4] + part[tid][5] + part[tid][6] + part[tid][7];
        out[b * NB + tid] = s;
    }
    __syncthreads();

    if (tid < 8 * NB) {                       // cols: 8 partials per col
        int c = tid >> 3, k = tid & 7;
        float s = 0.0f;
#pragma unroll
        for (int j = 0; j < 9; ++j) {
            int r = k + 8 * j;
            if (r < NB) s += jf[r * NB + c];
        }
        part[c][k] = s;
    }
    __syncthreads();
    if (tid < NB) {
        float s = part[tid][0] + part[tid][1] + part[tid][2] + part[tid][3] +
                  part[tid][4] + part[tid][5] + part[tid][6] + part[tid][7];
        out[2 * NB + b * NB + tid] = s;
    }
}

extern "C" void kernel_launch(void* const* d_in, const int* in_sizes, int n_in,
                              void* d_out, int out_size, void* d_ws,
                              size_t ws_size, hipStream_t stream) {
    const float* src = (const float*)d_in[0];
    const float* tgt = (const float*)d_in[1];
    float* out = (float*)d_out;
    float4* P = (float4*)((char*)d_ws + 64);
    unsigned long long* J = (unsigned long long*)((char*)d_ws + 4160);
    const int nvox = in_sizes[0] / 2;              // 512000
    const int n4 = nvox / 4;                       // 128000
    const double inv = 1.0 / ((double)nvox * (double)SCALE);

    k_prep<<<dim3(MMBLK, 2), dim3(1024), 0, stream>>>(src, tgt, P, J, n4);
    k_hist<<<dim3(MMBLK, 2), dim3(HTPB), 0, stream>>>(src, tgt, P, J, n4);
    k_norm<<<dim3(2), dim3(1024), 0, stream>>>(J, out, inv);
}

// Round 19
// 22.146 us; speedup vs baseline: 1.1904x; 1.1904x over previous
//
#include <hip/hip_runtime.h>
#include <float.h>

#define NB 68                 // padded bins (64 + 2*2)
#define NJ (NB * NB)          // 4624 joint bins
#define NSLICE 4              // J slices (flush chain depth ~31; r17 optimum)
#define HTPB 1024             // k_hist threads per block
#define MMBLK 125             // blocks per batch (125*1024 = 128000 float4s)
#define SCALE 8192.0f         // 2^13 fixed-point scale: whole-batch bin total
                              // <= 512000*0.444*8192 = 1.86e9 < 2^32 -> u32 J

// ws layout (bytes):
// [64 .. 64+2*128*16)  P: per-block minmax partials, float4 {smx,smn,tmx,tmn}
// [4160 .. +NSLICE*2*NJ*4)  J: u32 joint totals [slice][b][NJ]

// Kernel 1: minmax block partials + zero J slices. One float4 of src+tgt
// per thread (all loads in flight), block reduce, one plain float4 store.
__global__ __launch_bounds__(1024) void k_prep(const float* __restrict__ src,
                                               const float* __restrict__ tgt,
                                               float4* __restrict__ P,
                                               unsigned* __restrict__ J,
                                               int n4) {
    __shared__ float red[16][4];
    const int b = blockIdx.y;
    const int lin = (b * gridDim.x + blockIdx.x) * 1024 + threadIdx.x;
    if (lin < NSLICE * 2 * NJ) J[lin] = 0u;

    const int i = blockIdx.x * 1024 + threadIdx.x;
    float smx = -FLT_MAX, smn = FLT_MAX, tmx = -FLT_MAX, tmn = FLT_MAX;
    if (i < n4) {
        float4 v = ((const float4*)src)[(size_t)b * n4 + i];
        float4 w = ((const float4*)tgt)[(size_t)b * n4 + i];
        smx = fmaxf(fmaxf(v.x, v.y), fmaxf(v.z, v.w));
        smn = fminf(fminf(v.x, v.y), fminf(v.z, v.w));
        tmx = fmaxf(fmaxf(w.x, w.y), fmaxf(w.z, w.w));
        tmn = fminf(fminf(w.x, w.y), fminf(w.z, w.w));
    }
#pragma unroll
    for (int m = 1; m < 64; m <<= 1) {
        smx = fmaxf(smx, __shfl_xor(smx, m));
        smn = fminf(smn, __shfl_xor(smn, m));
        tmx = fmaxf(tmx, __shfl_xor(tmx, m));
        tmn = fminf(tmn, __shfl_xor(tmn, m));
    }
    const int wave = threadIdx.x >> 6;
    if ((threadIdx.x & 63) == 0) {
        red[wave][0] = smx;
        red[wave][1] = smn;
        red[wave][2] = tmx;
        red[wave][3] = tmn;
    }
    __syncthreads();
    if (threadIdx.x == 0) {
#pragma unroll
        for (int k = 1; k < 16; ++k) {
            smx = fmaxf(smx, red[k][0]);
            smn = fminf(smn, red[k][1]);
            tmx = fmaxf(tmx, red[k][2]);
            tmn = fminf(tmn, red[k][3]);
        }
        P[b * 128 + blockIdx.x] = make_float4(smx, smn, tmx, tmn);
    }
}

__device__ __forceinline__ float bspl(float d) {
    float ad = fabsf(d);
    float a = (3.0f * ad * ad * ad - 6.0f * ad * ad + 4.0f) * (1.0f / 6.0f);
    float t = 2.0f - ad;
    float c = t * t * t * (1.0f / 6.0f);
    return ad < 1.0f ? a : (ad < 2.0f ? c : 0.0f);
}

__device__ __forceinline__ void vox1(float sv, float tv, unsigned* jh,
                                     float spad, float sinv, float tpad,
                                     float tinv) {
    float posS = (sv - spad) * sinv;
    float fS = floorf(posS);
    fS = fminf(fmaxf(fS, 2.0f), 65.0f);
    int si = (int)fS - 1;
    float dS = posS - fS;
    float a[4] = {bspl(dS + 1.0f), bspl(dS), bspl(dS - 1.0f), bspl(dS - 2.0f)};

    float posT = (tv - tpad) * tinv;
    float fT = floorf(posT);
    fT = fminf(fmaxf(fT, 2.0f), 65.0f);
    int ti = (int)fT - 1;
    float dT = posT - fT;
    float bb[4] = {bspl(dT + 1.0f), bspl(dT), bspl(dT - 1.0f), bspl(dT - 2.0f)};

    unsigned* base = jh + si * NB + ti;
#pragma unroll
    for (int r = 0; r < 4; ++r) {
#pragma unroll
        for (int c = 0; c < 4; ++c) {
            unsigned q = (unsigned)(a[r] * bb[c] * SCALE + 0.5f);
            atomicAdd(&base[r * NB + c], q);
        }
    }
}

// Kernel 2: 1024 threads/block, 125 blocks/batch (1 float4/thread,
// 16 waves/CU), LDS u32 hist (2 lane-interleaved copies). u32 atomic
// flush into slice (bx & 3) with per-block rotation (chain depth ~31,
// half the bytes of the u64 flush). Integer -> deterministic.
__global__ __launch_bounds__(HTPB) void k_hist(
    const float* __restrict__ src, const float* __restrict__ tgt,
    const float4* __restrict__ P, unsigned* __restrict__ J, int n4) {
    __shared__ unsigned lh[2 * NJ];
    __shared__ float pmm[8], mmv[4];
    const int tid = threadIdx.x;
    const int b = blockIdx.y;

    // inline reduce of the 125 minmax partials (2 waves)
    if (tid < 128) {
        float smx = -FLT_MAX, smn = FLT_MAX, tmx = -FLT_MAX, tmn = FLT_MAX;
        if (tid < MMBLK) {
            float4 v = P[b * 128 + tid];
            smx = v.x; smn = v.y; tmx = v.z; tmn = v.w;
        }
#pragma unroll
        for (int m = 1; m < 64; m <<= 1) {
            smx = fmaxf(smx, __shfl_xor(smx, m));
            smn = fminf(smn, __shfl_xor(smn, m));
            tmx = fmaxf(tmx, __shfl_xor(tmx, m));
            tmn = fminf(tmn, __shfl_xor(tmn, m));
        }
        if ((tid & 63) == 0) {
            int w = tid >> 6;
            pmm[w * 4 + 0] = smx;
            pmm[w * 4 + 1] = smn;
            pmm[w * 4 + 2] = tmx;
            pmm[w * 4 + 3] = tmn;
        }
    }
    // zero LDS hist concurrently
    uint4* z4 = (uint4*)lh;
    const uint4 zz = make_uint4(0u, 0u, 0u, 0u);
    for (int i = tid; i < (2 * NJ) / 4; i += HTPB) z4[i] = zz;
    __syncthreads();
    if (tid == 0) {
        mmv[0] = fmaxf(pmm[0], pmm[4]);   // smx
        mmv[1] = fminf(pmm[1], pmm[5]);   // smn
        mmv[2] = fmaxf(pmm[2], pmm[6]);   // tmx
        mmv[3] = fminf(pmm[3], pmm[7]);   // tmn
    }
    __syncthreads();

    const float sbw = (mmv[0] - mmv[1]) * (1.0f / 64.0f);
    const float tbw = (mmv[2] - mmv[3]) * (1.0f / 64.0f);
    const float sinv = 1.0f / sbw, tinv = 1.0f / tbw;
    const float spad = mmv[1] - 2.0f * sbw;
    const float tpad = mmv[3] - 2.0f * tbw;

    unsigned* jh = lh + (tid & 1) * NJ;    // lane-interleaved copies
    const int i0 = blockIdx.x * HTPB + tid;
    if (i0 < n4) {
        float4 sA = ((const float4*)src)[(size_t)b * n4 + i0];
        float4 tA = ((const float4*)tgt)[(size_t)b * n4 + i0];
        vox1(sA.x, tA.x, jh, spad, sinv, tpad, tinv);
        vox1(sA.y, tA.y, jh, spad, sinv, tpad, tinv);
        vox1(sA.z, tA.z, jh, spad, sinv, tpad, tinv);
        vox1(sA.w, tA.w, jh, spad, sinv, tpad, tinv);
    }
    __syncthreads();

    // rotated, sliced flush (u32)
    const int rot = (blockIdx.x * 1327) % NJ;
    unsigned* Jb = J + ((size_t)(blockIdx.x & (NSLICE - 1)) * 2 + b) * NJ;
    for (int k = tid; k < NJ; k += HTPB) {
        int i = k + rot;
        if (i >= NJ) i -= NJ;
        unsigned s = lh[i] + lh[NJ + i];
        if (s) atomicAdd(&Jb[i], s);
    }
}

// Kernel 3: one 1024-thread block per batch. Sum the 4 u32 J slices while
// staging into LDS (emitting joint density), then row/col sums as 8-way
// parallel partials over LDS. Analytic total nvox*2^13.
__global__ __launch_bounds__(1024) void k_norm(
    const unsigned* __restrict__ J, float* __restrict__ out, double inv) {
    __shared__ float jf[NJ];
    __shared__ float part[NB][8];
    const int b = blockIdx.x;
    const int tid = threadIdx.x;

    for (int i = tid; i < NJ; i += 1024) {
        unsigned s = 0u;                      // batch total per bin < 2^32
#pragma unroll
        for (int sl = 0; sl < NSLICE; ++sl)
            s += J[((size_t)sl * 2 + b) * NJ + i];
        float f = (float)((double)s * inv);
        jf[i] = f;
        out[4 * NB + b * NJ + i] = f;
    }
    __syncthreads();

    if (tid < 8 * NB) {                       // rows: 8 partials per row
        int r = tid >> 3, k = tid & 7;
        float s = 0.0f;
#pragma unroll
        for (int j = 0; j < 9; ++j) {
            int c = k + 8 * j;
            if (c < NB) s += jf[r * NB + c];
        }
        part[r][k] = s;
    }
    __syncthreads();
    if (tid < NB) {
        float s = part[tid][0] + part[tid][1] + part[tid][2] + part[tid][3] +
                  part[tid][4] + part[tid][5] + part[tid][6] + part[tid][7];
        out[b * NB + tid] = s;
    }
    __syncthreads();

    if (tid < 8 * NB) {                       // cols: 8 partials per col
        int c = tid >> 3, k = tid & 7;
        float s = 0.0f;
#pragma unroll
        for (int j = 0; j < 9; ++j) {
            int r = k + 8 * j;
            if (r < NB) s += jf[r * NB + c];
        }
        part[c][k] = s;
    }
    __syncthreads();
    if (tid < NB) {
        float s = part[tid][0] + part[tid][1] + part[tid][2] + part[tid][3] +
                  part[tid][4] + part[tid][5] + part[tid][6] + part[tid][7];
        out[2 * NB + b * NB + tid] = s;
    }
}

extern "C" void kernel_launch(void* const* d_in, const int* in_sizes, int n_in,
                              void* d_out, int out_size, void* d_ws,
                              size_t ws_size, hipStream_t stream) {
    const float* src = (const float*)d_in[0];
    const float* tgt = (const float*)d_in[1];
    float* out = (float*)d_out;
    float4* P = (float4*)((char*)d_ws + 64);
    unsigned* J = (unsigned*)((char*)d_ws + 4160);
    const int nvox = in_sizes[0] / 2;              // 512000
    const int n4 = nvox / 4;                       // 128000
    const double inv = 1.0 / ((double)nvox * (double)SCALE);

    k_prep<<<dim3(MMBLK, 2), dim3(1024), 0, stream>>>(src, tgt, P, J, n4);
    k_hist<<<dim3(MMBLK, 2), dim3(HTPB), 0, stream>>>(src, tgt, P, J, n4);
    k_norm<<<dim3(2), dim3(1024), 0, stream>>>(J, out, inv);
}

// Round 21
// 22.068 us; speedup vs baseline: 1.1947x; 1.0036x over previous
//
#include <hip/hip_runtime.h>
#include <float.h>

#define NB 68                 // padded bins (64 + 2*2)
#define NJ (NB * NB)          // 4624 joint bins
#define NSLICE 4              // J slices (flush chain depth ~31; r17 optimum)
#define HTPB 1024             // k_hist threads per block
#define MMBLK 125             // blocks per batch (125*1024 = 128000 float4s)
#define SCALE 16384.0f        // 2^14: worst-case one-bin batch total
                              // 512000*0.444*16384 = 3.7e9 < 2^32 -> u32 J
#define LHSZ (2 * NJ + 8)     // two copies + 1-word shift pad + alignment

// ws layout (bytes):
// [64 .. 64+2*128*16)  P: per-block minmax partials, float4 {smx,smn,tmx,tmn}
// [4160 .. +NSLICE*2*NJ*4)  J: u32 joint totals [slice][b][NJ]

// Kernel 1: minmax block partials + zero J slices. One float4 of src+tgt
// per thread (all loads in flight), block reduce, one plain float4 store.
__global__ __launch_bounds__(1024) void k_prep(const float* __restrict__ src,
                                               const float* __restrict__ tgt,
                                               float4* __restrict__ P,
                                               unsigned* __restrict__ J,
                                               int n4) {
    __shared__ float red[16][4];
    const int b = blockIdx.y;
    const int lin = (b * gridDim.x + blockIdx.x) * 1024 + threadIdx.x;
    if (lin < NSLICE * 2 * NJ) J[lin] = 0u;

    const int i = blockIdx.x * 1024 + threadIdx.x;
    float smx = -FLT_MAX, smn = FLT_MAX, tmx = -FLT_MAX, tmn = FLT_MAX;
    if (i < n4) {
        float4 v = ((const float4*)src)[(size_t)b * n4 + i];
        float4 w = ((const float4*)tgt)[(size_t)b * n4 + i];
        smx = fmaxf(fmaxf(v.x, v.y), fmaxf(v.z, v.w));
        smn = fminf(fminf(v.x, v.y), fminf(v.z, v.w));
        tmx = fmaxf(fmaxf(w.x, w.y), fmaxf(w.z, w.w));
        tmn = fminf(fminf(w.x, w.y), fminf(w.z, w.w));
    }
#pragma unroll
    for (int m = 1; m < 64; m <<= 1) {
        smx = fmaxf(smx, __shfl_xor(smx, m));
        smn = fminf(smn, __shfl_xor(smn, m));
        tmx = fmaxf(tmx, __shfl_xor(tmx, m));
        tmn = fminf(tmn, __shfl_xor(tmn, m));
    }
    const int wave = threadIdx.x >> 6;
    if ((threadIdx.x & 63) == 0) {
        red[wave][0] = smx;
        red[wave][1] = smn;
        red[wave][2] = tmx;
        red[wave][3] = tmn;
    }
    __syncthreads();
    if (threadIdx.x == 0) {
#pragma unroll
        for (int k = 1; k < 16; ++k) {
            smx = fmaxf(smx, red[k][0]);
            smn = fminf(smn, red[k][1]);
            tmx = fmaxf(tmx, red[k][2]);
            tmn = fminf(tmn, red[k][3]);
        }
        P[b * 128 + blockIdx.x] = make_float4(smx, smn, tmx, tmn);
    }
}

__device__ __forceinline__ float bspl(float d) {
    float ad = fabsf(d);
    float a = (3.0f * ad * ad * ad - 6.0f * ad * ad + 4.0f) * (1.0f / 6.0f);
    float t = 2.0f - ad;
    float c = t * t * t * (1.0f / 6.0f);
    return ad < 1.0f ? a : (ad < 2.0f ? c : 0.0f);
}

// Packed-u64 tap deposit: 8 ds_add_u64 per voxel (was 16 ds_add_u32).
// Copy chosen by ti parity so the u64 pair boundary is 8-byte aligned:
// copy0 = lh[0..), normal layout; copy1 = lh[NJ+1..), shifted one u32.
// Low-lane carry impossible: per-copy per-bin <= 4096*0.444*16384 = 3e7.
__device__ __forceinline__ void vox1(float sv, float tv, unsigned* lh,
                                     float spad, float sinv, float tpad,
                                     float tinv) {
    float posS = (sv - spad) * sinv;
    float fS = floorf(posS);
    fS = fminf(fmaxf(fS, 2.0f), 65.0f);
    int si = (int)fS - 1;
    float dS = posS - fS;
    float a[4] = {bspl(dS + 1.0f), bspl(dS), bspl(dS - 1.0f), bspl(dS - 2.0f)};

    float posT = (tv - tpad) * tinv;
    float fT = floorf(posT);
    fT = fminf(fmaxf(fT, 2.0f), 65.0f);
    int ti = (int)fT - 1;
    float dT = posT - fT;
    float b0 = bspl(dT + 1.0f), b1 = bspl(dT), b2 = bspl(dT - 1.0f),
          b3 = bspl(dT - 2.0f);

    unsigned* base = lh + ((ti & 1) ? (NJ + 1) : 0) + si * NB + ti;
#pragma unroll
    for (int r = 0; r < 4; ++r) {
        unsigned q0 = (unsigned)(a[r] * b0 * SCALE + 0.5f);
        unsigned q1 = (unsigned)(a[r] * b1 * SCALE + 0.5f);
        unsigned q2 = (unsigned)(a[r] * b2 * SCALE + 0.5f);
        unsigned q3 = (unsigned)(a[r] * b3 * SCALE + 0.5f);
        atomicAdd((unsigned long long*)(base + r * NB),
                  (unsigned long long)q0 | ((unsigned long long)q1 << 32));
        atomicAdd((unsigned long long*)(base + r * NB + 2),
                  (unsigned long long)q2 | ((unsigned long long)q3 << 32));
    }
}

// Kernel 2: 1024 threads/block, 125 blocks/batch (1 float4/thread,
// 16 waves/CU). LDS u32 hist, 2 parity-selected copies, packed u64
// deposits. u32 atomic flush into slice (bx & 3) with per-block rotation.
// Integer -> deterministic.
__global__ __launch_bounds__(HTPB) void k_hist(
    const float* __restrict__ src, const float* __restrict__ tgt,
    const float4* __restrict__ P, unsigned* __restrict__ J, int n4) {
    __shared__ __align__(16) unsigned lh[LHSZ];
    __shared__ float pmm[8], mmv[4];
    const int tid = threadIdx.x;
    const int b = blockIdx.y;

    // inline reduce of the 125 minmax partials (2 waves)
    if (tid < 128) {
        float smx = -FLT_MAX, smn = FLT_MAX, tmx = -FLT_MAX, tmn = FLT_MAX;
        if (tid < MMBLK) {
            float4 v = P[b * 128 + tid];
            smx = v.x; smn = v.y; tmx = v.z; tmn = v.w;
        }
#pragma unroll
        for (int m = 1; m < 64; m <<= 1) {
            smx = fmaxf(smx, __shfl_xor(smx, m));
            smn = fminf(smn, __shfl_xor(smn, m));
            tmx = fmaxf(tmx, __shfl_xor(tmx, m));
            tmn = fminf(tmn, __shfl_xor(tmn, m));
        }
        if ((tid & 63) == 0) {
            int w = tid >> 6;
            pmm[w * 4 + 0] = smx;
            pmm[w * 4 + 1] = smn;
            pmm[w * 4 + 2] = tmx;
            pmm[w * 4 + 3] = tmn;
        }
    }
    // zero LDS hist concurrently
    uint4* z4 = (uint4*)lh;
    const uint4 zz = make_uint4(0u, 0u, 0u, 0u);
    for (int i = tid; i < LHSZ / 4; i += HTPB) z4[i] = zz;
    __syncthreads();
    if (tid == 0) {
        mmv[0] = fmaxf(pmm[0], pmm[4]);   // smx
        mmv[1] = fminf(pmm[1], pmm[5]);   // smn
        mmv[2] = fmaxf(pmm[2], pmm[6]);   // tmx
        mmv[3] = fminf(pmm[3], pmm[7]);   // tmn
    }
    __syncthreads();

    const float sbw = (mmv[0] - mmv[1]) * (1.0f / 64.0f);
    const float tbw = (mmv[2] - mmv[3]) * (1.0f / 64.0f);
    const float sinv = 1.0f / sbw, tinv = 1.0f / tbw;
    const float spad = mmv[1] - 2.0f * sbw;
    const float tpad = mmv[3] - 2.0f * tbw;

    const int i0 = blockIdx.x * HTPB + tid;
    if (i0 < n4) {
        float4 sA = ((const float4*)src)[(size_t)b * n4 + i0];
        float4 tA = ((const float4*)tgt)[(size_t)b * n4 + i0];
        vox1(sA.x, tA.x, lh, spad, sinv, tpad, tinv);
        vox1(sA.y, tA.y, lh, spad, sinv, tpad, tinv);
        vox1(sA.z, tA.z, lh, spad, sinv, tpad, tinv);
        vox1(sA.w, tA.w, lh, spad, sinv, tpad, tinv);
    }
    __syncthreads();

    // rotated, sliced flush (u32): copy1 logical bin i at lh[NJ+1+i]
    const int rot = (blockIdx.x * 1327) % NJ;
    unsigned* Jb = J + ((size_t)(blockIdx.x & (NSLICE - 1)) * 2 + b) * NJ;
    for (int k = tid; k < NJ; k += HTPB) {
        int i = k + rot;
        if (i >= NJ) i -= NJ;
        unsigned s = lh[i] + lh[NJ + 1 + i];
        if (s) atomicAdd(&Jb[i], s);
    }
}

// Kernel 3: one 1024-thread block per batch. Sum the 4 u32 J slices while
// staging into LDS (emitting joint density), then row/col sums as 8-way
// parallel partials over LDS. Analytic total nvox*2^14.
__global__ __launch_bounds__(1024) void k_norm(
    const unsigned* __restrict__ J, float* __restrict__ out, double inv) {
    __shared__ float jf[NJ];
    __shared__ float part[NB][8];
    const int b = blockIdx.x;
    const int tid = threadIdx.x;

    for (int i = tid; i < NJ; i += 1024) {
        unsigned s = 0u;                      // batch total per bin < 2^32
#pragma unroll
        for (int sl = 0; sl < NSLICE; ++sl)
            s += J[((size_t)sl * 2 + b) * NJ + i];
        float f = (float)((double)s * inv);
        jf[i] = f;
        out[4 * NB + b * NJ + i] = f;
    }
    __syncthreads();

    if (tid < 8 * NB) {                       // rows: 8 partials per row
        int r = tid >> 3, k = tid & 7;
        float s = 0.0f;
#pragma unroll
        for (int j = 0; j < 9; ++j) {
            int c = k + 8 * j;
            if (c < NB) s += jf[r * NB + c];
        }
        part[r][k] = s;
    }
    __syncthreads();
    if (tid < NB) {
        float s = part[tid][0] + part[tid][1] + part[tid][2] + part[tid][3] +
                  part[tid][4] + part[tid][5] + part[tid][6] + part[tid][7];
        out[b * NB + tid] = s;
    }
    __syncthreads();

    if (tid < 8 * NB) {                       // cols: 8 partials per col
        int c = tid >> 3, k = tid & 7;
        float s = 0.0f;
#pragma unroll
        for (int j = 0; j < 9; ++j) {
            int r = k + 8 * j;
            if (r < NB) s += jf[r * NB + c];
        }
        part[c][k] = s;
    }
    __syncthreads();
    if (tid < NB) {
        float s = part[tid][0] + part[tid][1] + part[tid][2] + part[tid][3] +
                  part[tid][4] + part[tid][5] + part[tid][6] + part[tid][7];
        out[2 * NB + b * NB + tid] = s;
    }
}

extern "C" void kernel_launch(void* const* d_in, const int* in_sizes, int n_in,
                              void* d_out, int out_size, void* d_ws,
                              size_t ws_size, hipStream_t stream) {
    const float* src = (const float*)d_in[0];
    const float* tgt = (const float*)d_in[1];
    float* out = (float*)d_out;
    float4* P = (float4*)((char*)d_ws + 64);
    unsigned* J = (unsigned*)((char*)d_ws + 4160);
    const int nvox = in_sizes[0] / 2;              // 512000
    const int n4 = nvox / 4;                       // 128000
    const double inv = 1.0 / ((double)nvox * (double)SCALE);

    k_prep<<<dim3(MMBLK, 2), dim3(1024), 0, stream>>>(src, tgt, P, J, n4);
    k_hist<<<dim3(MMBLK, 2), dim3(HTPB), 0, stream>>>(src, tgt, P, J, n4);
    k_norm<<<dim3(2), dim3(1024), 0, stream>>>(J, out, inv);
}